// Round 11
// baseline (570.709 us; speedup 1.0000x reference)
//
#include <hip/hip_runtime.h>
#include <hip/hip_bf16.h>

#define NN 20000
#define EE 320000
#define HD 128   // hidden

typedef _Float16 half8 __attribute__((ext_vector_type(8)));
typedef _Float16 half4 __attribute__((ext_vector_type(4)));
typedef _Float16 half2v __attribute__((ext_vector_type(2)));
typedef float floatx4 __attribute__((ext_vector_type(4)));

__device__ __forceinline__ float silu_f(float x){ return x / (1.f + __expf(-x)); }

__device__ __forceinline__ bool ei_is64(const int* __restrict__ ei){
  return (ei[1] | ei[3] | ei[5] | ei[7]) == 0;
}
__device__ __forceinline__ int ei_src(const int* __restrict__ ei, int e, bool is64){
  return is64 ? ei[2*(size_t)e] : ei[e];
}
__device__ __forceinline__ int ei_dst(const int* __restrict__ ei, int e, bool is64){
  return is64 ? ei[2*(size_t)EE + 2*(size_t)e] : ei[EE + e];
}

__global__ __launch_bounds__(256) void sentinel_kernel(float* __restrict__ out, int n, float val){
  int i = blockIdx.x*256 + threadIdx.x;
  if (i < n) out[i] = val;
}

// ---------------- weight packing: MFMA B-fragment layouts ----------------
__global__ __launch_bounds__(256) void pack_w1p_kernel(const float* __restrict__ cw1,
                                                       _Float16* __restrict__ w1p){
  int idx = blockIdx.x*256 + threadIdx.x;   // 768 blocks exact
  int j   = idx & 7;
  int ln  = (idx >> 3) & 63;
  int rest= idx >> 9;
  int cb  = rest & 15;
  int rest2 = rest >> 4;
  int ks  = rest2 & 3;
  int l   = rest2 >> 2;
  int k = ks*32 + (ln>>4)*8 + j;
  int c = cb*16 + (ln&15);
  float v = (c < 128) ? cw1[(size_t)l*33152 + (size_t)k*128 + c]
                      : cw1[(size_t)l*33152 + (size_t)(128+k)*128 + (c-128)];
  w1p[idx] = (_Float16)v;
}
__global__ __launch_bounds__(256) void pack_w2p_kernel(const float* __restrict__ cw2,
                                                       _Float16* __restrict__ w2p){
  int idx = blockIdx.x*256 + threadIdx.x;   // 384 blocks exact
  int j   = idx & 7;
  int ln  = (idx >> 3) & 63;
  int rest= idx >> 9;
  int cb  = rest & 7;
  int rest2 = rest >> 3;
  int ks  = rest2 & 3;
  int l   = rest2 >> 2;
  int k = ks*32 + (ln>>4)*8 + j;
  int c = cb*16 + (ln&15);
  w2p[idx] = (_Float16)cw2[(size_t)l*16384 + (size_t)k*128 + c];
}

// ---------------- CSR build ----------------
__global__ __launch_bounds__(256) void count_kernel(const int* __restrict__ ei, int* __restrict__ cnt){
  int e = blockIdx.x*256 + threadIdx.x;   // EE/256 exact
  bool is64 = ei_is64(ei);
  atomicAdd(&cnt[ei_dst(ei, e, is64)], 1);
}

__global__ __launch_bounds__(1024) void scan_kernel(int* __restrict__ cntcur,
                                                    int* __restrict__ row_start,
                                                    float* __restrict__ invd){
  __shared__ int part[1024];
  const int t = threadIdx.x;
  const int base = t*20;
  int loc[20];
  int sum = 0;
  #pragma unroll
  for (int i=0;i<20;++i){
    int n = base+i;
    int v = (n < NN) ? cntcur[n] : 0;
    loc[i] = sum; sum += v;
  }
  part[t] = sum;
  __syncthreads();
  for (int off=1; off<1024; off<<=1){
    int v = (t >= off) ? part[t-off] : 0;
    __syncthreads();
    part[t] += v;
    __syncthreads();
  }
  int pre = (t > 0) ? part[t-1] : 0;
  #pragma unroll
  for (int i=0;i<20;++i){
    int n = base+i;
    if (n < NN){
      int rs = pre + loc[i];
      int deg = ((i<19)?loc[i+1]:sum) - loc[i];
      row_start[n] = rs;
      invd[n] = (deg > 0) ? 1.f/(float)deg : 0.f;
      cntcur[n] = rs;
    }
  }
  if (t == 1023) row_start[NN] = part[1023];
}

__global__ __launch_bounds__(256) void scatter_kernel(const int* __restrict__ ei,
                                                      const float* __restrict__ eattr,
                                                      int* __restrict__ cur,
                                                      int* __restrict__ src_s,
                                                      _Float16* __restrict__ ea_s){
  int e = blockIdx.x*256 + threadIdx.x;   // EE/256 exact
  bool is64 = ei_is64(ei);
  int s = ei_src(ei, e, is64);
  int d = ei_dst(ei, e, is64);
  int pos = atomicAdd(&cur[d], 1);
  src_s[pos] = s;
  half4 ea;
  ea[0] = (_Float16)eattr[(size_t)e*3+0];
  ea[1] = (_Float16)eattr[(size_t)e*3+1];
  ea[2] = (_Float16)eattr[(size_t)e*3+2];
  ea[3] = (_Float16)0.f;
  *(half4*)(ea_s + (size_t)pos*4) = ea;
}

// ---------------- encoder: x(N,14) -> h(N,128) fp32 + hh fp16 ----------------
__global__ __launch_bounds__(128) void encoder_kernel(
    const float* __restrict__ x, const float* __restrict__ w1, const float* __restrict__ b1,
    const float* __restrict__ w2, const float* __restrict__ b2,
    float* __restrict__ h, _Float16* __restrict__ hh)
{
  __shared__ float xs[16][14];
  __shared__ float s1[16][128];
  const int n0 = blockIdx.x*16;
  const int tid = threadIdx.x;
  for (int idx=tid; idx<224; idx+=128){
    int i = idx/14, k = idx%14;
    xs[i][k] = x[(size_t)(n0+i)*14 + k];
  }
  __syncthreads();
  const int o = tid;
  float acc[16];
  float bv = b1[o];
  #pragma unroll
  for (int i=0;i<16;++i) acc[i] = bv;
  for (int k=0;k<14;++k){
    float w = w1[k*128+o];
    #pragma unroll
    for (int i=0;i<16;++i) acc[i] += xs[i][k]*w;
  }
  #pragma unroll
  for (int i=0;i<16;++i) s1[i][o] = silu_f(acc[i]);
  __syncthreads();
  float bv2 = b2[o];
  #pragma unroll
  for (int i=0;i<16;++i) acc[i] = bv2;
  for (int k=0;k<128;k+=4){
    float w0=w2[(k+0)*128+o], w1v=w2[(k+1)*128+o], w2v=w2[(k+2)*128+o], w3v=w2[(k+3)*128+o];
    #pragma unroll
    for (int i=0;i<16;++i){
      float4 sv = *(const float4*)&s1[i][k];
      acc[i] += sv.x*w0 + sv.y*w1v + sv.z*w2v + sv.w*w3v;
    }
  }
  #pragma unroll
  for (int i=0;i<16;++i){
    size_t off = (size_t)(n0+i)*HD + o;
    h[off] = acc[i];
    hh[off] = (_Float16)acc[i];
  }
}

// ---------------- proj (MFMA): UV(N,256) = [hh·W1d + b1 | hh·W1s] fp16 ----------------
__global__ __launch_bounds__(256) void proj_kernel(
    const _Float16* __restrict__ hh, const _Float16* __restrict__ w1p,
    const float* __restrict__ b1, _Float16* __restrict__ UV)
{
  const int tid = threadIdx.x;
  const int wv  = tid >> 6;
  const int ln  = tid & 63;
  const int q   = ln >> 4;
  const int m   = ln & 15;
  const int n0  = (blockIdx.x*4 + wv)*16;
  if (n0 >= NN) return;

  floatx4 acc[16];
  #pragma unroll
  for (int cb=0;cb<16;++cb) acc[cb] = (floatx4){0.f,0.f,0.f,0.f};

  #pragma unroll
  for (int ks=0; ks<4; ++ks){
    half8 a = *(const half8*)(hh + (size_t)(n0+m)*HD + ks*32 + q*8);
    const _Float16* wb = w1p + (size_t)(ks*16*64 + ln)*8;
    #pragma unroll
    for (int cb=0; cb<16; ++cb){
      half8 b = *(const half8*)(wb + (size_t)cb*512);
      acc[cb] = __builtin_amdgcn_mfma_f32_16x16x32_f16(a, b, acc[cb], 0,0,0);
    }
  }
  #pragma unroll
  for (int cb=0; cb<16; ++cb){
    const int c = cb*16 + m;
    const float bias = (c < 128) ? b1[c] : 0.f;
    #pragma unroll
    for (int r=0;r<4;++r)
      UV[(size_t)(n0+q*4+r)*256 + c] = (_Float16)(acc[cb][r] + bias);
  }
}

// ---------------- edge_agg v2: 4 edges in flight per wave ----------------
// wave = 1 node; quad q handles edge e0+q; lane m covers channels 8m..8m+7 (half8 gather).
// Rolling prefetch of the next 4-edge group -> up to 8 outstanding gathers/wave.
__global__ __launch_bounds__(256) void edge_agg_kernel(
    const _Float16* __restrict__ UV, const int* __restrict__ row_start,
    const int* __restrict__ src_s, const _Float16* __restrict__ ea_s,
    const float* __restrict__ w1e,      // conv_w1 + l*33152 + 32768 (3 rows x 128)
    const float* __restrict__ invd, _Float16* __restrict__ S)
{
  const int tid = threadIdx.x;
  const int wv  = __builtin_amdgcn_readfirstlane(tid >> 6);
  const int ln  = tid & 63;
  const int q   = ln >> 4;
  const int m   = ln & 15;
  const int n   = blockIdx.x*4 + wv;   // grid NN/4 = 5000 exact
  const int c0  = m*8;

  // per-lane weights (channels c0..c0+7) and U
  float we0[8], we1[8], we2[8], u[8];
  {
    float4 a0 = *(const float4*)(w1e +   0 + c0), a1 = *(const float4*)(w1e +   0 + c0 + 4);
    float4 b0 = *(const float4*)(w1e + 128 + c0), b1 = *(const float4*)(w1e + 128 + c0 + 4);
    float4 g0 = *(const float4*)(w1e + 256 + c0), g1 = *(const float4*)(w1e + 256 + c0 + 4);
    we0[0]=a0.x;we0[1]=a0.y;we0[2]=a0.z;we0[3]=a0.w;we0[4]=a1.x;we0[5]=a1.y;we0[6]=a1.z;we0[7]=a1.w;
    we1[0]=b0.x;we1[1]=b0.y;we1[2]=b0.z;we1[3]=b0.w;we1[4]=b1.x;we1[5]=b1.y;we1[6]=b1.z;we1[7]=b1.w;
    we2[0]=g0.x;we2[1]=g0.y;we2[2]=g0.z;we2[3]=g0.w;we2[4]=g1.x;we2[5]=g1.y;we2[6]=g1.z;we2[7]=g1.w;
    half8 uh = *(const half8*)(UV + (size_t)n*256 + c0);
    #pragma unroll
    for (int j=0;j<8;++j) u[j] = (float)uh[j];
  }

  const int rs = row_start[n], re = row_start[n+1];
  float a[8];
  #pragma unroll
  for (int j=0;j<8;++j) a[j] = 0.f;

  if (re > rs){
    const int last = re - 1;
    int e  = rs + q;
    int ec = e < last ? e : last;
    int s  = src_s[ec];
    half8 v  = *(const half8*)(UV + (size_t)s*256 + 128 + c0);
    half4 ea = *(const half4*)(ea_s + (size_t)ec*4);
    for (int e0 = rs; e0 < re; e0 += 4){
      int en = e0 + 4;
      int s2 = 0; half8 v2 = {}; half4 ea2 = {};
      if (en < re){                          // wave-uniform
        int e2c = en + q; e2c = e2c < last ? e2c : last;
        s2  = src_s[e2c];
        v2  = *(const half8*)(UV + (size_t)s2*256 + 128 + c0);
        ea2 = *(const half4*)(ea_s + (size_t)e2c*4);
      }
      if (e0 + q < re){                      // quad-uniform mask
        const float e0f = (float)ea[0], e1f = (float)ea[1], e2f = (float)ea[2];
        #pragma unroll
        for (int j=0;j<8;++j){
          float p = u[j] + (float)v[j] + e0f*we0[j] + e1f*we1[j] + e2f*we2[j];
          a[j] += silu_f(p);
        }
      }
      s = s2; v = v2; ea = ea2;
      e += 4;
    }
  }
  // reduce across quads (butterfly on the two quad bits)
  #pragma unroll
  for (int j=0;j<8;++j){
    a[j] += __shfl_xor(a[j], 16);
    a[j] += __shfl_xor(a[j], 32);
  }
  if (q == 0){
    const float iv = invd[n];
    half8 o;
    #pragma unroll
    for (int j=0;j<8;++j) o[j] = (_Float16)(a[j]*iv);
    *(half8*)(S + (size_t)n*HD + c0) = o;
  }
}

// ---------------- node (MFMA): h += S·W2 + gate·b2 ; refresh hh ----------------
__global__ __launch_bounds__(256) void node_kernel(
    const _Float16* __restrict__ S, const _Float16* __restrict__ w2p,
    const float* __restrict__ b2, const float* __restrict__ invd,
    float* __restrict__ h, _Float16* __restrict__ hh)
{
  const int tid = threadIdx.x;
  const int wv  = tid >> 6;
  const int ln  = tid & 63;
  const int q   = ln >> 4;
  const int m   = ln & 15;
  const int n0  = (blockIdx.x*4 + wv)*16;
  if (n0 >= NN) return;

  floatx4 acc[8];
  #pragma unroll
  for (int cb=0;cb<8;++cb) acc[cb] = (floatx4){0.f,0.f,0.f,0.f};

  #pragma unroll
  for (int ks=0; ks<4; ++ks){
    half8 a = *(const half8*)(S + (size_t)(n0+m)*HD + ks*32 + q*8);
    const _Float16* wb = w2p + (size_t)(ks*8*64 + ln)*8;
    #pragma unroll
    for (int cb=0; cb<8; ++cb){
      half8 b = *(const half8*)(wb + (size_t)cb*512);
      acc[cb] = __builtin_amdgcn_mfma_f32_16x16x32_f16(a, b, acc[cb], 0,0,0);
    }
  }
  float gate[4];
  #pragma unroll
  for (int r=0;r<4;++r) gate[r] = (invd[n0 + q*4 + r] > 0.f) ? 1.f : 0.f;
  #pragma unroll
  for (int cb=0; cb<8; ++cb){
    const int c = cb*16 + m;
    const float bv = b2[c];
    #pragma unroll
    for (int r=0;r<4;++r){
      size_t off = (size_t)(n0+q*4+r)*HD + c;
      float hv = h[off] + acc[cb][r] + gate[r]*bv;
      h[off] = hv;
      hh[off] = (_Float16)hv;
    }
  }
}

// ---------------- decoder: 128 ->(silu) 128 ->(silu) 64 -> 9 ----------------
__global__ __launch_bounds__(128) void decoder_kernel(
    const float* __restrict__ h,
    const float* __restrict__ w1, const float* __restrict__ b1,
    const float* __restrict__ w2, const float* __restrict__ b2,
    const float* __restrict__ w3, const float* __restrict__ b3,
    float* __restrict__ out)
{
  __shared__ float ht[16][128];
  __shared__ float s1[16][128];
  __shared__ float s2[16][65];   // stride 65: breaks same-bank conflicts in final stage
  const int n0 = blockIdx.x*16;
  const int tid = threadIdx.x;
  for (int idx=tid; idx<2048; idx+=128){
    int i = idx>>7, k = idx&127;
    ht[i][k] = h[(size_t)(n0+i)*HD + k];
  }
  __syncthreads();
  {
    const int o = tid;
    float acc[16];
    float bv = b1[o];
    #pragma unroll
    for (int i=0;i<16;++i) acc[i] = bv;
    for (int k=0;k<128;k+=4){
      float w0=w1[(k+0)*128+o], w1v=w1[(k+1)*128+o], w2v=w1[(k+2)*128+o], w3v=w1[(k+3)*128+o];
      #pragma unroll
      for (int i=0;i<16;++i){
        float4 hv = *(const float4*)&ht[i][k];
        acc[i] += hv.x*w0 + hv.y*w1v + hv.z*w2v + hv.w*w3v;
      }
    }
    #pragma unroll
    for (int i=0;i<16;++i) s1[i][o] = silu_f(acc[i]);
  }
  __syncthreads();
  {
    const int o = tid & 63;
    const int hf = tid >> 6;
    float acc[8];
    float bv = b2[o];
    #pragma unroll
    for (int i=0;i<8;++i) acc[i] = bv;
    for (int k=0;k<128;k+=4){
      float w0=w2[(k+0)*64+o], w1v=w2[(k+1)*64+o], w2v=w2[(k+2)*64+o], w3v=w2[(k+3)*64+o];
      #pragma unroll
      for (int i=0;i<8;++i){
        float4 sv = *(const float4*)&s1[hf*8+i][k];
        acc[i] += sv.x*w0 + sv.y*w1v + sv.z*w2v + sv.w*w3v;
      }
    }
    #pragma unroll
    for (int i=0;i<8;++i) s2[hf*8+i][o] = silu_f(acc[i]);
  }
  __syncthreads();
  for (int idx = tid; idx < 144; idx += 128){   // loop, NOT "if" — the r1-r5 bug
    int i = idx/9, oo = idx%9;
    float a = b3[oo];
    #pragma unroll 8
    for (int k=0;k<64;++k) a += s2[i][k]*w3[k*9+oo];
    out[(size_t)(n0+i)*9 + oo] = a;
  }
}

// ---------------- workspace layout (35,389,888 B) ----------------
constexpr size_t OFF_H    = 0;                         // 10,240,000
constexpr size_t OFF_HH   = 10240000;                  //  5,120,000
constexpr size_t OFF_UV   = 15360000;                  // 10,240,000
constexpr size_t OFF_S    = 25600000;                  //  5,120,000 (fp16)
constexpr size_t OFF_INVD = 30720000;                  //     80,000
constexpr size_t OFF_RS   = 30800000;                  //     80,064
constexpr size_t OFF_CUR  = 30880064;                  //     80,000
constexpr size_t OFF_SRC  = 30960064;                  //  1,280,000
constexpr size_t OFF_EA   = 32240064;                  //  2,560,000
constexpr size_t OFF_W1P  = 34800064;                  //    393,216
constexpr size_t OFF_W2P  = 35193280;                  //    196,608
constexpr size_t WS_NEEDED= 35389888;

extern "C" void kernel_launch(void* const* d_in, const int* in_sizes, int n_in,
                              void* d_out, int out_size, void* d_ws, size_t ws_size,
                              hipStream_t stream)
{
  float* out = (float*)d_out;
  const int nout_blk = (out_size + 255)/256;

  static const int EXP_SIZES[17] = {280000,640000,960000,1792,128,16384,128,
                                    198912,768,98304,768,16384,128,8192,64,576,9};
  if (n_in != 17){
    sentinel_kernel<<<nout_blk, 256, 0, stream>>>(out, out_size, 2.0e7f + (float)n_in*1.0e3f);
    return;
  }
  for (int i = 0; i < 17; ++i){
    if (in_sizes[i] != EXP_SIZES[i]){
      int sz = in_sizes[i] < 99999 ? in_sizes[i] : 99999;
      sentinel_kernel<<<nout_blk, 256, 0, stream>>>(out, out_size,
          1.0e7f + (float)i*1.0e5f + (float)sz);
      return;
    }
  }
  if (ws_size < WS_NEEDED){
    sentinel_kernel<<<nout_blk, 256, 0, stream>>>(out, out_size, 1.0e6f);
    return;
  }

  const float* x       = (const float*)d_in[0];
  const int*   ei      = (const int*)  d_in[1];
  const float* eattr   = (const float*)d_in[2];
  const float* enc_w1  = (const float*)d_in[3];
  const float* enc_b1  = (const float*)d_in[4];
  const float* enc_w2  = (const float*)d_in[5];
  const float* enc_b2  = (const float*)d_in[6];
  const float* conv_w1 = (const float*)d_in[7];
  const float* conv_b1 = (const float*)d_in[8];
  const float* conv_w2 = (const float*)d_in[9];
  const float* conv_b2 = (const float*)d_in[10];
  const float* dec_w1  = (const float*)d_in[11];
  const float* dec_b1  = (const float*)d_in[12];
  const float* dec_w2  = (const float*)d_in[13];
  const float* dec_b2  = (const float*)d_in[14];
  const float* dec_w3  = (const float*)d_in[15];
  const float* dec_b3  = (const float*)d_in[16];

  char* ws = (char*)d_ws;
  float*    h     = (float*)   (ws + OFF_H);
  _Float16* hh    = (_Float16*)(ws + OFF_HH);
  _Float16* UV    = (_Float16*)(ws + OFF_UV);
  _Float16* S     = (_Float16*)(ws + OFF_S);
  float*    invd  = (float*)   (ws + OFF_INVD);
  int*      rstart= (int*)     (ws + OFF_RS);
  int*      cur   = (int*)     (ws + OFF_CUR);
  int*      src_s = (int*)     (ws + OFF_SRC);
  _Float16* ea_s  = (_Float16*)(ws + OFF_EA);
  _Float16* w1p   = (_Float16*)(ws + OFF_W1P);
  _Float16* w2p   = (_Float16*)(ws + OFF_W2P);

  hipMemsetAsync(cur, 0, (size_t)NN*sizeof(int), stream);

  pack_w1p_kernel<<<768, 256, 0, stream>>>(conv_w1, w1p);
  pack_w2p_kernel<<<384, 256, 0, stream>>>(conv_w2, w2p);
  count_kernel<<<EE/256, 256, 0, stream>>>(ei, cur);
  scan_kernel<<<1, 1024, 0, stream>>>(cur, rstart, invd);
  scatter_kernel<<<EE/256, 256, 0, stream>>>(ei, eattr, cur, src_s, ea_s);
  encoder_kernel<<<NN/16, 128, 0, stream>>>(x, enc_w1, enc_b1, enc_w2, enc_b2, h, hh);
  for (int l=0; l<6; ++l){
    proj_kernel<<<313, 256, 0, stream>>>(hh, w1p + (size_t)l*32768,
                                         conv_b1 + (size_t)l*128, UV);
    edge_agg_kernel<<<NN/4, 256, 0, stream>>>(UV, rstart, src_s, ea_s,
                                              conv_w1 + (size_t)l*33152 + 32768,
                                              invd, S);
    node_kernel<<<313, 256, 0, stream>>>(S, w2p + (size_t)l*16384,
                                         conv_b2 + (size_t)l*128, invd, h, hh);
  }
  decoder_kernel<<<NN/16, 128, 0, stream>>>(h, dec_w1, dec_b1, dec_w2, dec_b2,
                                            dec_w3, dec_b3, out);
}

// Round 12
// 561.968 us; speedup vs baseline: 1.0156x; 1.0156x over previous
//
#include <hip/hip_runtime.h>
#include <hip/hip_bf16.h>

#define NN 20000
#define EE 320000
#define HD 128   // hidden

typedef _Float16 half8 __attribute__((ext_vector_type(8)));
typedef _Float16 half4 __attribute__((ext_vector_type(4)));
typedef _Float16 half2v __attribute__((ext_vector_type(2)));
typedef float floatx4 __attribute__((ext_vector_type(4)));

__device__ __forceinline__ float silu_f(float x){ return x / (1.f + __expf(-x)); }

__device__ __forceinline__ bool ei_is64(const int* __restrict__ ei){
  return (ei[1] | ei[3] | ei[5] | ei[7]) == 0;
}
__device__ __forceinline__ int ei_src(const int* __restrict__ ei, int e, bool is64){
  return is64 ? ei[2*(size_t)e] : ei[e];
}
__device__ __forceinline__ int ei_dst(const int* __restrict__ ei, int e, bool is64){
  return is64 ? ei[2*(size_t)EE + 2*(size_t)e] : ei[EE + e];
}

__global__ __launch_bounds__(256) void sentinel_kernel(float* __restrict__ out, int n, float val){
  int i = blockIdx.x*256 + threadIdx.x;
  if (i < n) out[i] = val;
}

// ---------------- weight packing: MFMA B-fragment layouts ----------------
__global__ __launch_bounds__(256) void pack_w1p_kernel(const float* __restrict__ cw1,
                                                       _Float16* __restrict__ w1p){
  int idx = blockIdx.x*256 + threadIdx.x;   // 768 blocks exact
  int j   = idx & 7;
  int ln  = (idx >> 3) & 63;
  int rest= idx >> 9;
  int cb  = rest & 15;
  int rest2 = rest >> 4;
  int ks  = rest2 & 3;
  int l   = rest2 >> 2;
  int k = ks*32 + (ln>>4)*8 + j;
  int c = cb*16 + (ln&15);
  float v = (c < 128) ? cw1[(size_t)l*33152 + (size_t)k*128 + c]
                      : cw1[(size_t)l*33152 + (size_t)(128+k)*128 + (c-128)];
  w1p[idx] = (_Float16)v;
}
__global__ __launch_bounds__(256) void pack_w2p_kernel(const float* __restrict__ cw2,
                                                       _Float16* __restrict__ w2p){
  int idx = blockIdx.x*256 + threadIdx.x;   // 384 blocks exact
  int j   = idx & 7;
  int ln  = (idx >> 3) & 63;
  int rest= idx >> 9;
  int cb  = rest & 7;
  int rest2 = rest >> 3;
  int ks  = rest2 & 3;
  int l   = rest2 >> 2;
  int k = ks*32 + (ln>>4)*8 + j;
  int c = cb*16 + (ln&15);
  w2p[idx] = (_Float16)cw2[(size_t)l*16384 + (size_t)k*128 + c];
}
// decoder weights: dec_w1 (128x128 -> 4ks x 8cb), dec_w2 (128x64 -> 4ks x 4cb)
__global__ __launch_bounds__(256) void pack_dec_kernel(const float* __restrict__ dw1,
                                                       const float* __restrict__ dw2,
                                                       _Float16* __restrict__ w1dp,
                                                       _Float16* __restrict__ w2dp){
  int idx = blockIdx.x*256 + threadIdx.x;   // 96 blocks = 24576 exact
  if (idx < 16384){
    int j = idx & 7, ln = (idx>>3)&63, cb = (idx>>9)&7, ks = idx>>12;
    int k = ks*32 + (ln>>4)*8 + j;
    int c = cb*16 + (ln&15);
    w1dp[idx] = (_Float16)dw1[(size_t)k*128 + c];
  } else {
    int t = idx - 16384;
    int j = t & 7, ln = (t>>3)&63, cb = (t>>9)&3, ks = t>>11;
    int k = ks*32 + (ln>>4)*8 + j;
    int c = cb*16 + (ln&15);
    w2dp[t] = (_Float16)dw2[(size_t)k*64 + c];
  }
}

// ---------------- CSR build ----------------
__global__ __launch_bounds__(256) void count_kernel(const int* __restrict__ ei, int* __restrict__ cnt){
  int e = blockIdx.x*256 + threadIdx.x;   // EE/256 exact
  bool is64 = ei_is64(ei);
  atomicAdd(&cnt[ei_dst(ei, e, is64)], 1);
}

__global__ __launch_bounds__(1024) void scan_kernel(int* __restrict__ cntcur,
                                                    int* __restrict__ row_start,
                                                    float* __restrict__ invd){
  __shared__ int part[1024];
  const int t = threadIdx.x;
  const int base = t*20;
  int loc[20];
  int sum = 0;
  #pragma unroll
  for (int i=0;i<20;++i){
    int n = base+i;
    int v = (n < NN) ? cntcur[n] : 0;
    loc[i] = sum; sum += v;
  }
  part[t] = sum;
  __syncthreads();
  for (int off=1; off<1024; off<<=1){
    int v = (t >= off) ? part[t-off] : 0;
    __syncthreads();
    part[t] += v;
    __syncthreads();
  }
  int pre = (t > 0) ? part[t-1] : 0;
  #pragma unroll
  for (int i=0;i<20;++i){
    int n = base+i;
    if (n < NN){
      int rs = pre + loc[i];
      int deg = ((i<19)?loc[i+1]:sum) - loc[i];
      row_start[n] = rs;
      invd[n] = (deg > 0) ? 1.f/(float)deg : 0.f;
      cntcur[n] = rs;
    }
  }
  if (t == 1023) row_start[NN] = part[1023];
}

__global__ __launch_bounds__(256) void scatter_kernel(const int* __restrict__ ei,
                                                      const float* __restrict__ eattr,
                                                      int* __restrict__ cur,
                                                      int* __restrict__ src_s,
                                                      _Float16* __restrict__ ea_s){
  int e = blockIdx.x*256 + threadIdx.x;   // EE/256 exact
  bool is64 = ei_is64(ei);
  int s = ei_src(ei, e, is64);
  int d = ei_dst(ei, e, is64);
  int pos = atomicAdd(&cur[d], 1);
  src_s[pos] = s;
  half4 ea;
  ea[0] = (_Float16)eattr[(size_t)e*3+0];
  ea[1] = (_Float16)eattr[(size_t)e*3+1];
  ea[2] = (_Float16)eattr[(size_t)e*3+2];
  ea[3] = (_Float16)0.f;
  *(half4*)(ea_s + (size_t)pos*4) = ea;
}

// ---------------- encoder: x(N,14) -> h(N,128) fp32 + hh fp16 ----------------
__global__ __launch_bounds__(128) void encoder_kernel(
    const float* __restrict__ x, const float* __restrict__ w1, const float* __restrict__ b1,
    const float* __restrict__ w2, const float* __restrict__ b2,
    float* __restrict__ h, _Float16* __restrict__ hh)
{
  __shared__ float xs[16][14];
  __shared__ float s1[16][128];
  const int n0 = blockIdx.x*16;
  const int tid = threadIdx.x;
  for (int idx=tid; idx<224; idx+=128){
    int i = idx/14, k = idx%14;
    xs[i][k] = x[(size_t)(n0+i)*14 + k];
  }
  __syncthreads();
  const int o = tid;
  float acc[16];
  float bv = b1[o];
  #pragma unroll
  for (int i=0;i<16;++i) acc[i] = bv;
  for (int k=0;k<14;++k){
    float w = w1[k*128+o];
    #pragma unroll
    for (int i=0;i<16;++i) acc[i] += xs[i][k]*w;
  }
  #pragma unroll
  for (int i=0;i<16;++i) s1[i][o] = silu_f(acc[i]);
  __syncthreads();
  float bv2 = b2[o];
  #pragma unroll
  for (int i=0;i<16;++i) acc[i] = bv2;
  for (int k=0;k<128;k+=4){
    float w0=w2[(k+0)*128+o], w1v=w2[(k+1)*128+o], w2v=w2[(k+2)*128+o], w3v=w2[(k+3)*128+o];
    #pragma unroll
    for (int i=0;i<16;++i){
      float4 sv = *(const float4*)&s1[i][k];
      acc[i] += sv.x*w0 + sv.y*w1v + sv.z*w2v + sv.w*w3v;
    }
  }
  #pragma unroll
  for (int i=0;i<16;++i){
    size_t off = (size_t)(n0+i)*HD + o;
    h[off] = acc[i];
    hh[off] = (_Float16)acc[i];
  }
}

// ---------------- proj (MFMA, layer 0 only): UV = [hh·W1d + b1 | hh·W1s] ----------------
__global__ __launch_bounds__(256) void proj_kernel(
    const _Float16* __restrict__ hh, const _Float16* __restrict__ w1p,
    const float* __restrict__ b1, _Float16* __restrict__ UV)
{
  const int tid = threadIdx.x;
  const int wv  = tid >> 6;
  const int ln  = tid & 63;
  const int q   = ln >> 4;
  const int m   = ln & 15;
  const int n0  = (blockIdx.x*4 + wv)*16;
  if (n0 >= NN) return;

  floatx4 acc[16];
  #pragma unroll
  for (int cb=0;cb<16;++cb) acc[cb] = (floatx4){0.f,0.f,0.f,0.f};

  #pragma unroll
  for (int ks=0; ks<4; ++ks){
    half8 a = *(const half8*)(hh + (size_t)(n0+m)*HD + ks*32 + q*8);
    const _Float16* wb = w1p + (size_t)(ks*16*64 + ln)*8;
    #pragma unroll
    for (int cb=0; cb<16; ++cb){
      half8 b = *(const half8*)(wb + (size_t)cb*512);
      acc[cb] = __builtin_amdgcn_mfma_f32_16x16x32_f16(a, b, acc[cb], 0,0,0);
    }
  }
  #pragma unroll
  for (int cb=0; cb<16; ++cb){
    const int c = cb*16 + m;
    const float bias = (c < 128) ? b1[c] : 0.f;
    #pragma unroll
    for (int r=0;r<4;++r)
      UV[(size_t)(n0+q*4+r)*256 + c] = (_Float16)(acc[cb][r] + bias);
  }
}

// ---------------- edge_agg (v1, best measured): per-node mean of silu(U+V[src]+ea·We) ----------------
__global__ __launch_bounds__(256) void edge_agg_kernel(
    const _Float16* __restrict__ UV, const int* __restrict__ row_start,
    const int* __restrict__ src_s, const _Float16* __restrict__ ea_s,
    const float* __restrict__ w1e, const float* __restrict__ invd,
    _Float16* __restrict__ S)
{
  const int tid = threadIdx.x;
  const int wv  = __builtin_amdgcn_readfirstlane(tid >> 6);
  const int ln  = tid & 63;
  const int n   = blockIdx.x*4 + wv;   // grid NN/4 = 5000 exact
  const int c0  = ln*2;

  const float2 wc0 = *(const float2*)(w1e +   0 + c0);
  const float2 wc1 = *(const float2*)(w1e + 128 + c0);
  const float2 wc2 = *(const float2*)(w1e + 256 + c0);

  half2v uvp = *(const half2v*)(UV + (size_t)n*256 + c0);
  const float u0 = (float)uvp[0], u1 = (float)uvp[1];

  const int rs = row_start[n], re = row_start[n+1];
  float a0 = 0.f, a1 = 0.f;
  if (re > rs){
    int s = src_s[rs];
    half4 ea = *(const half4*)(ea_s + (size_t)rs*4);
    half2v v = *(const half2v*)(UV + (size_t)s*256 + 128 + c0);
    for (int e = rs+1; e <= re; ++e){
      int s2 = 0; half4 ea2 = {}; half2v v2 = {};
      if (e < re){
        s2  = src_s[e];
        ea2 = *(const half4*)(ea_s + (size_t)e*4);
        v2  = *(const half2v*)(UV + (size_t)s2*256 + 128 + c0);
      }
      const float e0 = (float)ea[0], e1 = (float)ea[1], e2 = (float)ea[2];
      float p0 = u0 + (float)v[0] + e0*wc0.x + e1*wc1.x + e2*wc2.x;
      float p1 = u1 + (float)v[1] + e0*wc0.y + e1*wc1.y + e2*wc2.y;
      a0 += silu_f(p0);
      a1 += silu_f(p1);
      s = s2; ea = ea2; v = v2;
    }
  }
  const float iv = invd[n];
  half2v outv; outv[0] = (_Float16)(a0*iv); outv[1] = (_Float16)(a1*iv);
  *(half2v*)(S + (size_t)n*HD + c0) = outv;
}

// ---------------- node_proj: h += S·W2 + gate·b2 ; hh refresh ; fused proj(l+1) ----------------
// wave = 16 nodes. Tail wave-slots recompute group 1249 with stores guarded by `lead`
// (no early return -> __syncthreads is safe). LDS round-trip C-layout -> A-layout,
// row stride 136 halfs => 2-way bank aliasing only (free, m136).
__global__ __launch_bounds__(256) void node_proj_kernel(
    const _Float16* __restrict__ S, const _Float16* __restrict__ w2p,
    const float* __restrict__ b2, const float* __restrict__ invd,
    float* __restrict__ h, _Float16* __restrict__ hh,
    const _Float16* __restrict__ w1pn, const float* __restrict__ b1n,
    _Float16* __restrict__ UV, int do_proj)
{
  __shared__ _Float16 hl[4][16][136];
  const int tid = threadIdx.x;
  const int wv  = tid >> 6;
  const int ln  = tid & 63;
  const int q   = ln >> 4;
  const int m   = ln & 15;
  int g = blockIdx.x*4 + wv;            // 313 blocks -> 1252 slots for 1250 groups
  const bool lead = (g < 1250);
  if (g > 1249) g = 1249;
  const int n0 = g*16;

  floatx4 acc[8];
  #pragma unroll
  for (int cb=0;cb<8;++cb) acc[cb] = (floatx4){0.f,0.f,0.f,0.f};
  #pragma unroll
  for (int ks=0; ks<4; ++ks){
    half8 a = *(const half8*)(S + (size_t)(n0+m)*HD + ks*32 + q*8);
    const _Float16* wb = w2p + (size_t)(ks*8*64 + ln)*8;
    #pragma unroll
    for (int cb=0; cb<8; ++cb){
      half8 b = *(const half8*)(wb + (size_t)cb*512);
      acc[cb] = __builtin_amdgcn_mfma_f32_16x16x32_f16(a, b, acc[cb], 0,0,0);
    }
  }
  float gate[4];
  #pragma unroll
  for (int r=0;r<4;++r) gate[r] = (invd[n0 + q*4 + r] > 0.f) ? 1.f : 0.f;
  #pragma unroll
  for (int cb=0; cb<8; ++cb){
    const int c = cb*16 + m;
    const float bv = b2[c];
    #pragma unroll
    for (int r=0;r<4;++r){
      size_t off = (size_t)(n0+q*4+r)*HD + c;
      float hv = h[off] + acc[cb][r] + gate[r]*bv;
      if (lead){ h[off] = hv; hh[off] = (_Float16)hv; }
      hl[wv][q*4+r][c] = (_Float16)hv;
    }
  }
  __syncthreads();
  if (do_proj){
    floatx4 acc2[16];
    #pragma unroll
    for (int cb=0;cb<16;++cb) acc2[cb] = (floatx4){0.f,0.f,0.f,0.f};
    #pragma unroll
    for (int ks=0; ks<4; ++ks){
      half8 a = *(const half8*)&hl[wv][m][ks*32 + q*8];
      const _Float16* wb = w1pn + (size_t)(ks*16*64 + ln)*8;
      #pragma unroll
      for (int cb=0; cb<16; ++cb){
        half8 b = *(const half8*)(wb + (size_t)cb*512);
        acc2[cb] = __builtin_amdgcn_mfma_f32_16x16x32_f16(a, b, acc2[cb], 0,0,0);
      }
    }
    if (lead){
      #pragma unroll
      for (int cb=0; cb<16; ++cb){
        const int c = cb*16 + m;
        const float bias = (c < 128) ? b1n[c] : 0.f;
        #pragma unroll
        for (int r=0;r<4;++r)
          UV[(size_t)(n0+q*4+r)*256 + c] = (_Float16)(acc2[cb][r] + bias);
      }
    }
  }
}

// ---------------- decoder (MFMA stages 1-2): hh -> out(N,9) ----------------
__global__ __launch_bounds__(256) void decoder_kernel(
    const _Float16* __restrict__ hh,
    const _Float16* __restrict__ w1dp, const float* __restrict__ db1,
    const _Float16* __restrict__ w2dp, const float* __restrict__ db2,
    const float* __restrict__ dw3, const float* __restrict__ db3,
    float* __restrict__ out)
{
  __shared__ _Float16 d1[4][16][136];
  __shared__ float s2m[4][16][66];
  const int tid = threadIdx.x;
  const int wv  = tid >> 6;
  const int ln  = tid & 63;
  const int q   = ln >> 4;
  const int m   = ln & 15;
  int g = blockIdx.x*4 + wv;
  if (g > 1249) g = 1249;         // dup waves recompute same group; out writes identical
  const int n0 = g*16;

  floatx4 acc1[8];
  #pragma unroll
  for (int cb=0;cb<8;++cb) acc1[cb] = (floatx4){0.f,0.f,0.f,0.f};
  #pragma unroll
  for (int ks=0; ks<4; ++ks){
    half8 a = *(const half8*)(hh + (size_t)(n0+m)*HD + ks*32 + q*8);
    const _Float16* wb = w1dp + (size_t)(ks*8*64 + ln)*8;
    #pragma unroll
    for (int cb=0; cb<8; ++cb){
      half8 b = *(const half8*)(wb + (size_t)cb*512);
      acc1[cb] = __builtin_amdgcn_mfma_f32_16x16x32_f16(a, b, acc1[cb], 0,0,0);
    }
  }
  #pragma unroll
  for (int cb=0; cb<8; ++cb){
    const int c = cb*16 + m;
    const float bv = db1[c];
    #pragma unroll
    for (int r=0;r<4;++r)
      d1[wv][q*4+r][c] = (_Float16)silu_f(acc1[cb][r] + bv);
  }
  __syncthreads();
  floatx4 acc2[4];
  #pragma unroll
  for (int cb=0;cb<4;++cb) acc2[cb] = (floatx4){0.f,0.f,0.f,0.f};
  #pragma unroll
  for (int ks=0; ks<4; ++ks){
    half8 a = *(const half8*)&d1[wv][m][ks*32 + q*8];
    const _Float16* wb = w2dp + (size_t)(ks*4*64 + ln)*8;
    #pragma unroll
    for (int cb=0; cb<4; ++cb){
      half8 b = *(const half8*)(wb + (size_t)cb*512);
      acc2[cb] = __builtin_amdgcn_mfma_f32_16x16x32_f16(a, b, acc2[cb], 0,0,0);
    }
  }
  #pragma unroll
  for (int cb=0; cb<4; ++cb){
    const int c = cb*16 + m;
    const float bv = db2[c];
    #pragma unroll
    for (int r=0;r<4;++r)
      s2m[wv][q*4+r][c] = silu_f(acc2[cb][r] + bv);
  }
  __syncthreads();
  for (int idx = ln; idx < 144; idx += 64){
    int i = idx/9, oo = idx%9;
    float a = db3[oo];
    #pragma unroll 8
    for (int k=0;k<64;++k) a += s2m[wv][i][k]*dw3[k*9+oo];
    out[(size_t)(n0+i)*9 + oo] = a;
  }
}

// ---------------- workspace layout (35,439,040 B) ----------------
constexpr size_t OFF_H    = 0;                         // 10,240,000
constexpr size_t OFF_HH   = 10240000;                  //  5,120,000
constexpr size_t OFF_UV   = 15360000;                  // 10,240,000
constexpr size_t OFF_S    = 25600000;                  //  5,120,000 (fp16)
constexpr size_t OFF_INVD = 30720000;                  //     80,000
constexpr size_t OFF_RS   = 30800000;                  //     80,064
constexpr size_t OFF_CUR  = 30880064;                  //     80,000
constexpr size_t OFF_SRC  = 30960064;                  //  1,280,000
constexpr size_t OFF_EA   = 32240064;                  //  2,560,000
constexpr size_t OFF_W1P  = 34800064;                  //    393,216
constexpr size_t OFF_W2P  = 35193280;                  //    196,608
constexpr size_t OFF_DW1P = 35389888;                  //     32,768
constexpr size_t OFF_DW2P = 35422656;                  //     16,384
constexpr size_t WS_NEEDED= 35439040;

extern "C" void kernel_launch(void* const* d_in, const int* in_sizes, int n_in,
                              void* d_out, int out_size, void* d_ws, size_t ws_size,
                              hipStream_t stream)
{
  float* out = (float*)d_out;
  const int nout_blk = (out_size + 255)/256;

  static const int EXP_SIZES[17] = {280000,640000,960000,1792,128,16384,128,
                                    198912,768,98304,768,16384,128,8192,64,576,9};
  if (n_in != 17){
    sentinel_kernel<<<nout_blk, 256, 0, stream>>>(out, out_size, 2.0e7f + (float)n_in*1.0e3f);
    return;
  }
  for (int i = 0; i < 17; ++i){
    if (in_sizes[i] != EXP_SIZES[i]){
      int sz = in_sizes[i] < 99999 ? in_sizes[i] : 99999;
      sentinel_kernel<<<nout_blk, 256, 0, stream>>>(out, out_size,
          1.0e7f + (float)i*1.0e5f + (float)sz);
      return;
    }
  }
  if (ws_size < WS_NEEDED){
    sentinel_kernel<<<nout_blk, 256, 0, stream>>>(out, out_size, 1.0e6f);
    return;
  }

  const float* x       = (const float*)d_in[0];
  const int*   ei      = (const int*)  d_in[1];
  const float* eattr   = (const float*)d_in[2];
  const float* enc_w1  = (const float*)d_in[3];
  const float* enc_b1  = (const float*)d_in[4];
  const float* enc_w2  = (const float*)d_in[5];
  const float* enc_b2  = (const float*)d_in[6];
  const float* conv_w1 = (const float*)d_in[7];
  const float* conv_b1 = (const float*)d_in[8];
  const float* conv_w2 = (const float*)d_in[9];
  const float* conv_b2 = (const float*)d_in[10];
  const float* dec_w1  = (const float*)d_in[11];
  const float* dec_b1  = (const float*)d_in[12];
  const float* dec_w2  = (const float*)d_in[13];
  const float* dec_b2  = (const float*)d_in[14];
  const float* dec_w3  = (const float*)d_in[15];
  const float* dec_b3  = (const float*)d_in[16];

  char* ws = (char*)d_ws;
  float*    h     = (float*)   (ws + OFF_H);
  _Float16* hh    = (_Float16*)(ws + OFF_HH);
  _Float16* UV    = (_Float16*)(ws + OFF_UV);
  _Float16* S     = (_Float16*)(ws + OFF_S);
  float*    invd  = (float*)   (ws + OFF_INVD);
  int*      rstart= (int*)     (ws + OFF_RS);
  int*      cur   = (int*)     (ws + OFF_CUR);
  int*      src_s = (int*)     (ws + OFF_SRC);
  _Float16* ea_s  = (_Float16*)(ws + OFF_EA);
  _Float16* w1p   = (_Float16*)(ws + OFF_W1P);
  _Float16* w2p   = (_Float16*)(ws + OFF_W2P);
  _Float16* w1dp  = (_Float16*)(ws + OFF_DW1P);
  _Float16* w2dp  = (_Float16*)(ws + OFF_DW2P);

  hipMemsetAsync(cur, 0, (size_t)NN*sizeof(int), stream);

  pack_w1p_kernel<<<768, 256, 0, stream>>>(conv_w1, w1p);
  pack_w2p_kernel<<<384, 256, 0, stream>>>(conv_w2, w2p);
  pack_dec_kernel<<<96, 256, 0, stream>>>(dec_w1, dec_w2, w1dp, w2dp);
  count_kernel<<<EE/256, 256, 0, stream>>>(ei, cur);
  scan_kernel<<<1, 1024, 0, stream>>>(cur, rstart, invd);
  scatter_kernel<<<EE/256, 256, 0, stream>>>(ei, eattr, cur, src_s, ea_s);
  encoder_kernel<<<NN/16, 128, 0, stream>>>(x, enc_w1, enc_b1, enc_w2, enc_b2, h, hh);
  proj_kernel<<<313, 256, 0, stream>>>(hh, w1p, conv_b1, UV);   // layer 0 proj
  for (int l=0; l<6; ++l){
    edge_agg_kernel<<<NN/4, 256, 0, stream>>>(UV, rstart, src_s, ea_s,
                                              conv_w1 + (size_t)l*33152 + 32768,
                                              invd, S);
    const int lp = (l < 5) ? l+1 : 0;   // dummy valid ptrs for last layer
    node_proj_kernel<<<313, 256, 0, stream>>>(S, w2p + (size_t)l*16384,
                                              conv_b2 + (size_t)l*128, invd, h, hh,
                                              w1p + (size_t)lp*32768,
                                              conv_b1 + (size_t)lp*128,
                                              UV, (l < 5) ? 1 : 0);
  }
  decoder_kernel<<<313, 256, 0, stream>>>(hh, w1dp, dec_b1, w2dp, dec_b2,
                                          dec_w3, dec_b3, out);
}

// Round 13
// 523.800 us; speedup vs baseline: 1.0896x; 1.0729x over previous
//
#include <hip/hip_runtime.h>
#include <hip/hip_bf16.h>

#define NN 20000
#define EE 320000
#define HD 128   // hidden

typedef _Float16 half8 __attribute__((ext_vector_type(8)));
typedef _Float16 half4 __attribute__((ext_vector_type(4)));
typedef _Float16 half2v __attribute__((ext_vector_type(2)));
typedef float floatx4 __attribute__((ext_vector_type(4)));

// silu via HW rcp (1-ulp) instead of exact fp32 divide — the exact div is a
// ~5-instr chain and was ~40% of edge_agg's inner-loop VALU (r12 analysis).
__device__ __forceinline__ float silu_f(float x){
  float e = __expf(-x);
  return x * __builtin_amdgcn_rcpf(1.f + e);
}

__device__ __forceinline__ bool ei_is64(const int* __restrict__ ei){
  return (ei[1] | ei[3] | ei[5] | ei[7]) == 0;
}
__device__ __forceinline__ int ei_src(const int* __restrict__ ei, int e, bool is64){
  return is64 ? ei[2*(size_t)e] : ei[e];
}
__device__ __forceinline__ int ei_dst(const int* __restrict__ ei, int e, bool is64){
  return is64 ? ei[2*(size_t)EE + 2*(size_t)e] : ei[EE + e];
}

__global__ __launch_bounds__(256) void sentinel_kernel(float* __restrict__ out, int n, float val){
  int i = blockIdx.x*256 + threadIdx.x;
  if (i < n) out[i] = val;
}

// ---------------- merged weight packing (w1p | w2p | dec) ----------------
__global__ __launch_bounds__(256) void pack_all_kernel(const float* __restrict__ cw1,
                                                       const float* __restrict__ cw2,
                                                       const float* __restrict__ dw1,
                                                       const float* __restrict__ dw2,
                                                       _Float16* __restrict__ w1p,
                                                       _Float16* __restrict__ w2p,
                                                       _Float16* __restrict__ w1dp,
                                                       _Float16* __restrict__ w2dp){
  int idx = blockIdx.x*256 + threadIdx.x;   // 1248 blocks = 319488 exact
  if (idx < 196608){
    int j   = idx & 7;
    int ln  = (idx >> 3) & 63;
    int rest= idx >> 9;
    int cb  = rest & 15;
    int rest2 = rest >> 4;
    int ks  = rest2 & 3;
    int l   = rest2 >> 2;
    int k = ks*32 + (ln>>4)*8 + j;
    int c = cb*16 + (ln&15);
    float v = (c < 128) ? cw1[(size_t)l*33152 + (size_t)k*128 + c]
                        : cw1[(size_t)l*33152 + (size_t)(128+k)*128 + (c-128)];
    w1p[idx] = (_Float16)v;
  } else if (idx < 294912){
    int t = idx - 196608;
    int j   = t & 7;
    int ln  = (t >> 3) & 63;
    int rest= t >> 9;
    int cb  = rest & 7;
    int rest2 = rest >> 3;
    int ks  = rest2 & 3;
    int l   = rest2 >> 2;
    int k = ks*32 + (ln>>4)*8 + j;
    int c = cb*16 + (ln&15);
    w2p[t] = (_Float16)cw2[(size_t)l*16384 + (size_t)k*128 + c];
  } else {
    int t2 = idx - 294912;
    if (t2 < 16384){
      int j = t2 & 7, ln = (t2>>3)&63, cb = (t2>>9)&7, ks = t2>>12;
      int k = ks*32 + (ln>>4)*8 + j;
      int c = cb*16 + (ln&15);
      w1dp[t2] = (_Float16)dw1[(size_t)k*128 + c];
    } else {
      int t = t2 - 16384;
      int j = t & 7, ln = (t>>3)&63, cb = (t>>9)&3, ks = t>>11;
      int k = ks*32 + (ln>>4)*8 + j;
      int c = cb*16 + (ln&15);
      w2dp[t] = (_Float16)dw2[(size_t)k*64 + c];
    }
  }
}

// ---------------- CSR build ----------------
__global__ __launch_bounds__(256) void count_kernel(const int* __restrict__ ei, int* __restrict__ cnt){
  int e = blockIdx.x*256 + threadIdx.x;   // EE/256 exact
  bool is64 = ei_is64(ei);
  atomicAdd(&cnt[ei_dst(ei, e, is64)], 1);
}

__global__ __launch_bounds__(1024) void scan_kernel(int* __restrict__ cntcur,
                                                    int* __restrict__ row_start,
                                                    float* __restrict__ invd){
  __shared__ int part[1024];
  const int t = threadIdx.x;
  const int base = t*20;
  int loc[20];
  int sum = 0;
  #pragma unroll
  for (int i=0;i<20;++i){
    int n = base+i;
    int v = (n < NN) ? cntcur[n] : 0;
    loc[i] = sum; sum += v;
  }
  part[t] = sum;
  __syncthreads();
  for (int off=1; off<1024; off<<=1){
    int v = (t >= off) ? part[t-off] : 0;
    __syncthreads();
    part[t] += v;
    __syncthreads();
  }
  int pre = (t > 0) ? part[t-1] : 0;
  #pragma unroll
  for (int i=0;i<20;++i){
    int n = base+i;
    if (n < NN){
      int rs = pre + loc[i];
      int deg = ((i<19)?loc[i+1]:sum) - loc[i];
      row_start[n] = rs;
      invd[n] = (deg > 0) ? 1.f/(float)deg : 0.f;
      cntcur[n] = rs;
    }
  }
  if (t == 1023) row_start[NN] = part[1023];
}

__global__ __launch_bounds__(256) void scatter_kernel(const int* __restrict__ ei,
                                                      const float* __restrict__ eattr,
                                                      int* __restrict__ cur,
                                                      int* __restrict__ src_s,
                                                      _Float16* __restrict__ ea_s){
  int e = blockIdx.x*256 + threadIdx.x;   // EE/256 exact
  bool is64 = ei_is64(ei);
  int s = ei_src(ei, e, is64);
  int d = ei_dst(ei, e, is64);
  int pos = atomicAdd(&cur[d], 1);
  src_s[pos] = s*256;   // pre-scaled UV row element-offset (saves a v_mul per edge iter)
  half4 ea;
  ea[0] = (_Float16)eattr[(size_t)e*3+0];
  ea[1] = (_Float16)eattr[(size_t)e*3+1];
  ea[2] = (_Float16)eattr[(size_t)e*3+2];
  ea[3] = (_Float16)0.f;
  *(half4*)(ea_s + (size_t)pos*4) = ea;
}

// ---------------- encoder: x(N,14) -> h(N,128) fp32 + hh fp16 ----------------
__global__ __launch_bounds__(128) void encoder_kernel(
    const float* __restrict__ x, const float* __restrict__ w1, const float* __restrict__ b1,
    const float* __restrict__ w2, const float* __restrict__ b2,
    float* __restrict__ h, _Float16* __restrict__ hh)
{
  __shared__ float xs[16][14];
  __shared__ float s1[16][128];
  const int n0 = blockIdx.x*16;
  const int tid = threadIdx.x;
  for (int idx=tid; idx<224; idx+=128){
    int i = idx/14, k = idx%14;
    xs[i][k] = x[(size_t)(n0+i)*14 + k];
  }
  __syncthreads();
  const int o = tid;
  float acc[16];
  float bv = b1[o];
  #pragma unroll
  for (int i=0;i<16;++i) acc[i] = bv;
  for (int k=0;k<14;++k){
    float w = w1[k*128+o];
    #pragma unroll
    for (int i=0;i<16;++i) acc[i] += xs[i][k]*w;
  }
  #pragma unroll
  for (int i=0;i<16;++i) s1[i][o] = silu_f(acc[i]);
  __syncthreads();
  float bv2 = b2[o];
  #pragma unroll
  for (int i=0;i<16;++i) acc[i] = bv2;
  for (int k=0;k<128;k+=4){
    float w0=w2[(k+0)*128+o], w1v=w2[(k+1)*128+o], w2v=w2[(k+2)*128+o], w3v=w2[(k+3)*128+o];
    #pragma unroll
    for (int i=0;i<16;++i){
      float4 sv = *(const float4*)&s1[i][k];
      acc[i] += sv.x*w0 + sv.y*w1v + sv.z*w2v + sv.w*w3v;
    }
  }
  #pragma unroll
  for (int i=0;i<16;++i){
    size_t off = (size_t)(n0+i)*HD + o;
    h[off] = acc[i];
    hh[off] = (_Float16)acc[i];
  }
}

// ---------------- proj (MFMA, layer 0 only): UV = [hh·W1d + b1 | hh·W1s] ----------------
__global__ __launch_bounds__(256) void proj_kernel(
    const _Float16* __restrict__ hh, const _Float16* __restrict__ w1p,
    const float* __restrict__ b1, _Float16* __restrict__ UV)
{
  const int tid = threadIdx.x;
  const int wv  = tid >> 6;
  const int ln  = tid & 63;
  const int q   = ln >> 4;
  const int m   = ln & 15;
  const int n0  = (blockIdx.x*4 + wv)*16;
  if (n0 >= NN) return;

  floatx4 acc[16];
  #pragma unroll
  for (int cb=0;cb<16;++cb) acc[cb] = (floatx4){0.f,0.f,0.f,0.f};

  #pragma unroll
  for (int ks=0; ks<4; ++ks){
    half8 a = *(const half8*)(hh + (size_t)(n0+m)*HD + ks*32 + q*8);
    const _Float16* wb = w1p + (size_t)(ks*16*64 + ln)*8;
    #pragma unroll
    for (int cb=0; cb<16; ++cb){
      half8 b = *(const half8*)(wb + (size_t)cb*512);
      acc[cb] = __builtin_amdgcn_mfma_f32_16x16x32_f16(a, b, acc[cb], 0,0,0);
    }
  }
  #pragma unroll
  for (int cb=0; cb<16; ++cb){
    const int c = cb*16 + m;
    const float bias = (c < 128) ? b1[c] : 0.f;
    #pragma unroll
    for (int r=0;r<4;++r)
      UV[(size_t)(n0+q*4+r)*256 + c] = (_Float16)(acc[cb][r] + bias);
  }
}

// ---------------- edge_agg: per-node mean of silu(U+V[src]+ea·We) ----------------
// VALU-bound (r11 A/B test); rcp-silu + pre-scaled offsets cut the inner loop.
__global__ __launch_bounds__(256) void edge_agg_kernel(
    const _Float16* __restrict__ UV, const int* __restrict__ row_start,
    const int* __restrict__ src_s, const _Float16* __restrict__ ea_s,
    const float* __restrict__ w1e, const float* __restrict__ invd,
    _Float16* __restrict__ S)
{
  const int tid = threadIdx.x;
  const int wv  = __builtin_amdgcn_readfirstlane(tid >> 6);
  const int ln  = tid & 63;
  const int n   = blockIdx.x*4 + wv;   // grid NN/4 = 5000 exact
  const int c0  = ln*2;

  const float2 wc0 = *(const float2*)(w1e +   0 + c0);
  const float2 wc1 = *(const float2*)(w1e + 128 + c0);
  const float2 wc2 = *(const float2*)(w1e + 256 + c0);

  half2v uvp = *(const half2v*)(UV + (size_t)n*256 + c0);
  const float u0 = (float)uvp[0], u1 = (float)uvp[1];

  const int rs = row_start[n], re = row_start[n+1];
  float a0 = 0.f, a1 = 0.f;
  if (re > rs){
    int soff = src_s[rs];
    half4 ea = *(const half4*)(ea_s + (size_t)rs*4);
    half2v v = *(const half2v*)(UV + (size_t)soff + 128 + c0);
    for (int e = rs+1; e <= re; ++e){
      int soff2 = 0; half4 ea2 = {}; half2v v2 = {};
      if (e < re){
        soff2 = src_s[e];
        ea2 = *(const half4*)(ea_s + (size_t)e*4);
        v2  = *(const half2v*)(UV + (size_t)soff2 + 128 + c0);
      }
      const float e0 = (float)ea[0], e1 = (float)ea[1], e2 = (float)ea[2];
      float p0 = u0 + (float)v[0] + e0*wc0.x + e1*wc1.x + e2*wc2.x;
      float p1 = u1 + (float)v[1] + e0*wc0.y + e1*wc1.y + e2*wc2.y;
      a0 += silu_f(p0);
      a1 += silu_f(p1);
      soff = soff2; ea = ea2; v = v2;
    }
  }
  const float iv = invd[n];
  half2v outv; outv[0] = (_Float16)(a0*iv); outv[1] = (_Float16)(a1*iv);
  *(half2v*)(S + (size_t)n*HD + c0) = outv;
}

// ---------------- node_proj: h += S·W2 + gate·b2 ; hh refresh ; fused proj(l+1) ----------------
__global__ __launch_bounds__(256) void node_proj_kernel(
    const _Float16* __restrict__ S, const _Float16* __restrict__ w2p,
    const float* __restrict__ b2, const float* __restrict__ invd,
    float* __restrict__ h, _Float16* __restrict__ hh,
    const _Float16* __restrict__ w1pn, const float* __restrict__ b1n,
    _Float16* __restrict__ UV, int do_proj)
{
  __shared__ _Float16 hl[4][16][136];
  const int tid = threadIdx.x;
  const int wv  = tid >> 6;
  const int ln  = tid & 63;
  const int q   = ln >> 4;
  const int m   = ln & 15;
  int g = blockIdx.x*4 + wv;            // 313 blocks -> 1252 slots for 1250 groups
  const bool lead = (g < 1250);
  if (g > 1249) g = 1249;
  const int n0 = g*16;

  floatx4 acc[8];
  #pragma unroll
  for (int cb=0;cb<8;++cb) acc[cb] = (floatx4){0.f,0.f,0.f,0.f};
  #pragma unroll
  for (int ks=0; ks<4; ++ks){
    half8 a = *(const half8*)(S + (size_t)(n0+m)*HD + ks*32 + q*8);
    const _Float16* wb = w2p + (size_t)(ks*8*64 + ln)*8;
    #pragma unroll
    for (int cb=0; cb<8; ++cb){
      half8 b = *(const half8*)(wb + (size_t)cb*512);
      acc[cb] = __builtin_amdgcn_mfma_f32_16x16x32_f16(a, b, acc[cb], 0,0,0);
    }
  }
  float gate[4];
  #pragma unroll
  for (int r=0;r<4;++r) gate[r] = (invd[n0 + q*4 + r] > 0.f) ? 1.f : 0.f;
  #pragma unroll
  for (int cb=0; cb<8; ++cb){
    const int c = cb*16 + m;
    const float bv = b2[c];
    #pragma unroll
    for (int r=0;r<4;++r){
      size_t off = (size_t)(n0+q*4+r)*HD + c;
      float hv = h[off] + acc[cb][r] + gate[r]*bv;
      if (lead){ h[off] = hv; hh[off] = (_Float16)hv; }
      hl[wv][q*4+r][c] = (_Float16)hv;
    }
  }
  __syncthreads();
  if (do_proj){
    floatx4 acc2[16];
    #pragma unroll
    for (int cb=0;cb<16;++cb) acc2[cb] = (floatx4){0.f,0.f,0.f,0.f};
    #pragma unroll
    for (int ks=0; ks<4; ++ks){
      half8 a = *(const half8*)&hl[wv][m][ks*32 + q*8];
      const _Float16* wb = w1pn + (size_t)(ks*16*64 + ln)*8;
      #pragma unroll
      for (int cb=0; cb<16; ++cb){
        half8 b = *(const half8*)(wb + (size_t)cb*512);
        acc2[cb] = __builtin_amdgcn_mfma_f32_16x16x32_f16(a, b, acc2[cb], 0,0,0);
      }
    }
    if (lead){
      #pragma unroll
      for (int cb=0; cb<16; ++cb){
        const int c = cb*16 + m;
        const float bias = (c < 128) ? b1n[c] : 0.f;
        #pragma unroll
        for (int r=0;r<4;++r)
          UV[(size_t)(n0+q*4+r)*256 + c] = (_Float16)(acc2[cb][r] + bias);
      }
    }
  }
}

// ---------------- decoder (MFMA stages 1-2): hh -> out(N,9) ----------------
__global__ __launch_bounds__(256) void decoder_kernel(
    const _Float16* __restrict__ hh,
    const _Float16* __restrict__ w1dp, const float* __restrict__ db1,
    const _Float16* __restrict__ w2dp, const float* __restrict__ db2,
    const float* __restrict__ dw3, const float* __restrict__ db3,
    float* __restrict__ out)
{
  __shared__ _Float16 d1[4][16][136];
  __shared__ float s2m[4][16][66];
  const int tid = threadIdx.x;
  const int wv  = tid >> 6;
  const int ln  = tid & 63;
  const int q   = ln >> 4;
  const int m   = ln & 15;
  int g = blockIdx.x*4 + wv;
  if (g > 1249) g = 1249;         // dup waves recompute same group; out writes identical
  const int n0 = g*16;

  floatx4 acc1[8];
  #pragma unroll
  for (int cb=0;cb<8;++cb) acc1[cb] = (floatx4){0.f,0.f,0.f,0.f};
  #pragma unroll
  for (int ks=0; ks<4; ++ks){
    half8 a = *(const half8*)(hh + (size_t)(n0+m)*HD + ks*32 + q*8);
    const _Float16* wb = w1dp + (size_t)(ks*8*64 + ln)*8;
    #pragma unroll
    for (int cb=0; cb<8; ++cb){
      half8 b = *(const half8*)(wb + (size_t)cb*512);
      acc1[cb] = __builtin_amdgcn_mfma_f32_16x16x32_f16(a, b, acc1[cb], 0,0,0);
    }
  }
  #pragma unroll
  for (int cb=0; cb<8; ++cb){
    const int c = cb*16 + m;
    const float bv = db1[c];
    #pragma unroll
    for (int r=0;r<4;++r)
      d1[wv][q*4+r][c] = (_Float16)silu_f(acc1[cb][r] + bv);
  }
  __syncthreads();
  floatx4 acc2[4];
  #pragma unroll
  for (int cb=0;cb<4;++cb) acc2[cb] = (floatx4){0.f,0.f,0.f,0.f};
  #pragma unroll
  for (int ks=0; ks<4; ++ks){
    half8 a = *(const half8*)&d1[wv][m][ks*32 + q*8];
    const _Float16* wb = w2dp + (size_t)(ks*4*64 + ln)*8;
    #pragma unroll
    for (int cb=0; cb<4; ++cb){
      half8 b = *(const half8*)(wb + (size_t)cb*512);
      acc2[cb] = __builtin_amdgcn_mfma_f32_16x16x32_f16(a, b, acc2[cb], 0,0,0);
    }
  }
  #pragma unroll
  for (int cb=0; cb<4; ++cb){
    const int c = cb*16 + m;
    const float bv = db2[c];
    #pragma unroll
    for (int r=0;r<4;++r)
      s2m[wv][q*4+r][c] = silu_f(acc2[cb][r] + bv);
  }
  __syncthreads();
  for (int idx = ln; idx < 144; idx += 64){
    int i = idx/9, oo = idx%9;
    float a = db3[oo];
    #pragma unroll 8
    for (int k=0;k<64;++k) a += s2m[wv][i][k]*dw3[k*9+oo];
    out[(size_t)(n0+i)*9 + oo] = a;
  }
}

// ---------------- workspace layout (35,439,040 B) ----------------
constexpr size_t OFF_H    = 0;                         // 10,240,000
constexpr size_t OFF_HH   = 10240000;                  //  5,120,000
constexpr size_t OFF_UV   = 15360000;                  // 10,240,000
constexpr size_t OFF_S    = 25600000;                  //  5,120,000 (fp16)
constexpr size_t OFF_INVD = 30720000;                  //     80,000
constexpr size_t OFF_RS   = 30800000;                  //     80,064
constexpr size_t OFF_CUR  = 30880064;                  //     80,000
constexpr size_t OFF_SRC  = 30960064;                  //  1,280,000
constexpr size_t OFF_EA   = 32240064;                  //  2,560,000
constexpr size_t OFF_W1P  = 34800064;                  //    393,216
constexpr size_t OFF_W2P  = 35193280;                  //    196,608
constexpr size_t OFF_DW1P = 35389888;                  //     32,768
constexpr size_t OFF_DW2P = 35422656;                  //     16,384
constexpr size_t WS_NEEDED= 35439040;

extern "C" void kernel_launch(void* const* d_in, const int* in_sizes, int n_in,
                              void* d_out, int out_size, void* d_ws, size_t ws_size,
                              hipStream_t stream)
{
  float* out = (float*)d_out;
  const int nout_blk = (out_size + 255)/256;

  static const int EXP_SIZES[17] = {280000,640000,960000,1792,128,16384,128,
                                    198912,768,98304,768,16384,128,8192,64,576,9};
  if (n_in != 17){
    sentinel_kernel<<<nout_blk, 256, 0, stream>>>(out, out_size, 2.0e7f + (float)n_in*1.0e3f);
    return;
  }
  for (int i = 0; i < 17; ++i){
    if (in_sizes[i] != EXP_SIZES[i]){
      int sz = in_sizes[i] < 99999 ? in_sizes[i] : 99999;
      sentinel_kernel<<<nout_blk, 256, 0, stream>>>(out, out_size,
          1.0e7f + (float)i*1.0e5f + (float)sz);
      return;
    }
  }
  if (ws_size < WS_NEEDED){
    sentinel_kernel<<<nout_blk, 256, 0, stream>>>(out, out_size, 1.0e6f);
    return;
  }

  const float* x       = (const float*)d_in[0];
  const int*   ei      = (const int*)  d_in[1];
  const float* eattr   = (const float*)d_in[2];
  const float* enc_w1  = (const float*)d_in[3];
  const float* enc_b1  = (const float*)d_in[4];
  const float* enc_w2  = (const float*)d_in[5];
  const float* enc_b2  = (const float*)d_in[6];
  const float* conv_w1 = (const float*)d_in[7];
  const float* conv_b1 = (const float*)d_in[8];
  const float* conv_w2 = (const float*)d_in[9];
  const float* conv_b2 = (const float*)d_in[10];
  const float* dec_w1  = (const float*)d_in[11];
  const float* dec_b1  = (const float*)d_in[12];
  const float* dec_w2  = (const float*)d_in[13];
  const float* dec_b2  = (const float*)d_in[14];
  const float* dec_w3  = (const float*)d_in[15];
  const float* dec_b3  = (const float*)d_in[16];

  char* ws = (char*)d_ws;
  float*    h     = (float*)   (ws + OFF_H);
  _Float16* hh    = (_Float16*)(ws + OFF_HH);
  _Float16* UV    = (_Float16*)(ws + OFF_UV);
  _Float16* S     = (_Float16*)(ws + OFF_S);
  float*    invd  = (float*)   (ws + OFF_INVD);
  int*      rstart= (int*)     (ws + OFF_RS);
  int*      cur   = (int*)     (ws + OFF_CUR);
  int*      src_s = (int*)     (ws + OFF_SRC);
  _Float16* ea_s  = (_Float16*)(ws + OFF_EA);
  _Float16* w1p   = (_Float16*)(ws + OFF_W1P);
  _Float16* w2p   = (_Float16*)(ws + OFF_W2P);
  _Float16* w1dp  = (_Float16*)(ws + OFF_DW1P);
  _Float16* w2dp  = (_Float16*)(ws + OFF_DW2P);

  hipMemsetAsync(cur, 0, (size_t)NN*sizeof(int), stream);

  pack_all_kernel<<<1248, 256, 0, stream>>>(conv_w1, conv_w2, dec_w1, dec_w2,
                                            w1p, w2p, w1dp, w2dp);
  count_kernel<<<EE/256, 256, 0, stream>>>(ei, cur);
  scan_kernel<<<1, 1024, 0, stream>>>(cur, rstart, invd);
  scatter_kernel<<<EE/256, 256, 0, stream>>>(ei, eattr, cur, src_s, ea_s);
  encoder_kernel<<<NN/16, 128, 0, stream>>>(x, enc_w1, enc_b1, enc_w2, enc_b2, h, hh);
  proj_kernel<<<313, 256, 0, stream>>>(hh, w1p, conv_b1, UV);   // layer 0 proj
  for (int l=0; l<6; ++l){
    edge_agg_kernel<<<NN/4, 256, 0, stream>>>(UV, rstart, src_s, ea_s,
                                              conv_w1 + (size_t)l*33152 + 32768,
                                              invd, S);
    const int lp = (l < 5) ? l+1 : 0;   // dummy valid ptrs for last layer
    node_proj_kernel<<<313, 256, 0, stream>>>(S, w2p + (size_t)l*16384,
                                              conv_b2 + (size_t)l*128, invd, h, hh,
                                              w1p + (size_t)lp*32768,
                                              conv_b1 + (size_t)lp*128,
                                              UV, (l < 5) ? 1 : 0);
  }
  decoder_kernel<<<313, 256, 0, stream>>>(hh, w1dp, dec_b1, w2dp, dec_b2,
                                          dec_w3, dec_b3, out);
}